// Round 26
// baseline (127.927 us; speedup 1.0000x reference)
//
#include <hip/hip_runtime.h>
#include <hip/hip_bf16.h>

// AdaConv2d: per-sample conv, kernel = base * mask[label[b]] (oc-indep mask).
// B=64, IC=OC=64, H=W=112, 3x3, pad 1. fp32 in/out.
//
// Round 25: move A off the LDS pipe. Stream model: LDS-read (54 b128/wave/ck,
// one shared pipe/CU) ~60us is the dominant stream; MFMA 24 (4 SIMDs), fetch
// 17, write 33. A-frags (18/54 reads) come from a 9.2KB/ck L1-resident table
// shared by both CU blocks -> read A DIRECTLY from global wf2 per tap (2
// L1-hit loads + 4 B ds_reads + 8 MFMAs), delete A-LDS staging (-36.9KB LDS).
// LDS stream 54->36 reads (floor ~40us); VMEM/L1 absorbs A with latency
// hidden across 8 waves. B staging + T1 XCD swizzle = R24 verbatim.

#define HH 112
#define WW 112
#define ICn 64
#define OCn 64
#define FUSE_EPOCH 9
#define NPIX (HH * WW)

typedef __attribute__((ext_vector_type(8)))  short  short8;
typedef __attribute__((ext_vector_type(8)))  unsigned short bf8;
typedef __attribute__((ext_vector_type(16))) float  f32x16;
typedef unsigned int u32;

#define WF_BYTES ((size_t)4 * 64 * 576 * 2)

static __device__ __forceinline__ unsigned short f2bf(float v) {
    __hip_bfloat16 hb = __float2bfloat16(v);
    return *reinterpret_cast<unsigned short*>(&hb);
}

// -------- fused weights: wf2[d][ck][t][h][oc][8e], ic = ck*16+h*8+e --------
__global__ __launch_bounds__(256)
void fuse_w_kernel(const float* __restrict__ kb, const float* __restrict__ km,
                   unsigned short* __restrict__ wf2)
{
    int idx = blockIdx.x * 256 + threadIdx.x;
    if (idx >= 4 * 4 * 9 * 2 * 64 * 8) return;
    int e  = idx & 7;
    int oc = (idx >> 3) & 63;
    int h  = (idx >> 9) & 1;
    int r  = idx >> 10;          // t + 9*(ck + 4*d)
    int t  = r % 9; r /= 9;
    int ck = r & 3;
    int d  = r >> 2;
    int ic = ck * 16 + h * 8 + e;
    wf2[idx] = f2bf(kb[(oc * ICn + ic) * 9 + t] * km[(d * ICn + ic) * 9 + t]);
}

// ------------------- fused main: direct-x implicit GEMM -------------------
__global__ __launch_bounds__(256, 2)
void adaconv_fused(const float* __restrict__ x,
                   const unsigned short* __restrict__ wf2,
                   const int* __restrict__ label,
                   const int* __restrict__ epoch,
                   float* __restrict__ out)
{
    // B: [6 rows][2 hh][114 px][8 ic] bf16 = 21888 B per buffer (A: none)
    __shared__ unsigned short Bb[2][10944];

    const int tid  = threadIdx.x;
    // T1: XCD-bijective swizzle. 1792 blocks = 8 XCD x 224; XCD owns 8 samples.
    const int lid  = blockIdx.x;
    const int wgid = (lid & 7) * 224 + (lid >> 3);
    const int b    = wgid / 28;
    const int y0   = (wgid % 28) * 4;
    const int w    = tid >> 6;           // wave 0..3 = out-row y0+w
    const int lane = tid & 63;
    const int ln   = lane & 31;
    const int h    = lane >> 5;          // K-half

    int d = (epoch[0] >= FUSE_EPOCH) ? 0 : label[b];
    d &= 3;
    const unsigned short* wfd = wf2 + (size_t)d * 36864;

    // ---- per-thread B-staging descriptors (672 items, 3 rounds) ----
    const float* ga[12];
    int  lbase[3];
    bool wact[3], gval[3];
    #pragma unroll
    for (int r = 0; r < 3; ++r) {
        int c = r * 256 + tid;
        bool a = (c < 672);
        int cc = a ? c : 671;
        int seg = cc % 28;
        int q   = cc / 28;
        int icq = q & 1;
        int rh  = q >> 1;              // lr*2+hh
        int lr  = rh >> 1;
        int hh  = rh & 1;
        int gy  = y0 - 1 + lr;
        bool v  = ((unsigned)gy < 112u);
        wact[r] = a;
        gval[r] = v;
        lbase[r] = (rh * 114 + 4 * seg + 1) * 8 + icq * 4;
        int icl = hh * 8 + icq * 4;    // ic within 16-chunk
        #pragma unroll
        for (int i = 0; i < 4; ++i)
            ga[r * 4 + i] = x + ((size_t)(b * 64 + icl + i) * 112 + (v ? gy : 0)) * 112 + 4 * seg;
    }

    f32x16 acc[2][4];
    #pragma unroll
    for (int m = 0; m < 2; ++m)
        #pragma unroll
        for (int j = 0; j < 4; ++j)
            #pragma unroll
            for (int k = 0; k < 16; ++k) acc[m][j][k] = 0.f;

    const int bb = (w * 228 + h * 114 + ln) * 8;   // + (kh*228+kw+j*32)*8
    const int ag = h * 512 + ln * 8;               // global A lane offset

    // ---- prologue: zero edge px {0,113} in both buffers; stage B(0) ----
    if (tid < 48) {
        int bz = tid / 24, z = tid % 24;
        int rh = z >> 1, px = (z & 1) ? 113 : 0;
        bf8 zz = bf8{0,0,0,0,0,0,0,0};
        *reinterpret_cast<bf8*>(&Bb[bz][(rh * 114 + px) * 8]) = zz;
    }
    {
        float4 vl[12];
        #pragma unroll
        for (int r = 0; r < 3; ++r)
            if (wact[r])
                #pragma unroll
                for (int i = 0; i < 4; ++i)
                    vl[r * 4 + i] = *reinterpret_cast<const float4*>(ga[r * 4 + i]);
        #pragma unroll
        for (int r = 0; r < 3; ++r) {
            if (!wact[r]) continue;
            float c0[4] = {vl[r*4+0].x, vl[r*4+0].y, vl[r*4+0].z, vl[r*4+0].w};
            float c1[4] = {vl[r*4+1].x, vl[r*4+1].y, vl[r*4+1].z, vl[r*4+1].w};
            float c2[4] = {vl[r*4+2].x, vl[r*4+2].y, vl[r*4+2].z, vl[r*4+2].w};
            float c3[4] = {vl[r*4+3].x, vl[r*4+3].y, vl[r*4+3].z, vl[r*4+3].w};
            #pragma unroll
            for (int p = 0; p < 4; ++p) {
                float f0 = gval[r] ? c0[p] : 0.f;
                float f1 = gval[r] ? c1[p] : 0.f;
                float f2 = gval[r] ? c2[p] : 0.f;
                float f3 = gval[r] ? c3[p] : 0.f;
                __hip_bfloat162 u01 = __float22bfloat162_rn(make_float2(f0, f1));
                __hip_bfloat162 u23 = __float22bfloat162_rn(make_float2(f2, f3));
                uint2 wv;
                wv.x = *reinterpret_cast<unsigned*>(&u01);
                wv.y = *reinterpret_cast<unsigned*>(&u23);
                *reinterpret_cast<uint2*>(&Bb[0][lbase[r] + p * 8]) = wv;
            }
        }
        __syncthreads();
    }

    // ---- main loop: loadB(nxt) -> compute(cur, A from global) -> write(nxt) ----
    #pragma unroll
    for (int ck = 0; ck < 4; ++ck) {
        const int cur = ck & 1, nxt = cur ^ 1;
        float4 vl[12];
        if (ck < 3) {
            #pragma unroll
            for (int r = 0; r < 3; ++r)
                if (wact[r])
                    #pragma unroll
                    for (int i = 0; i < 4; ++i)
                        vl[r * 4 + i] = *reinterpret_cast<const float4*>(
                            ga[r * 4 + i] + (size_t)(ck + 1) * 200704);
            __builtin_amdgcn_sched_barrier(0);   // keep B-load issues above compute
        }

        const unsigned short* Bc = Bb[cur];
        const unsigned short* Ag = wfd + ck * 9216 + ag;
        #pragma unroll
        for (int kh = 0; kh < 3; ++kh) {
            #pragma unroll
            for (int kw = 0; kw < 3; ++kw) {
                const int t = kh * 3 + kw;
                short8 a0 = *reinterpret_cast<const short8*>(Ag + t * 1024);
                short8 a1 = *reinterpret_cast<const short8*>(Ag + t * 1024 + 256);
                #pragma unroll
                for (int j = 0; j < 4; ++j) {
                    short8 bj = *reinterpret_cast<const short8*>(
                        &Bc[bb + (kh * 228 + kw + j * 32) * 8]);
                    acc[0][j] = __builtin_amdgcn_mfma_f32_32x32x16_bf16(a0, bj, acc[0][j], 0, 0, 0);
                    acc[1][j] = __builtin_amdgcn_mfma_f32_32x32x16_bf16(a1, bj, acc[1][j], 0, 0, 0);
                }
            }
        }

        if (ck < 3) {
            #pragma unroll
            for (int r = 0; r < 3; ++r) {
                if (!wact[r]) continue;
                float c0[4] = {vl[r*4+0].x, vl[r*4+0].y, vl[r*4+0].z, vl[r*4+0].w};
                float c1[4] = {vl[r*4+1].x, vl[r*4+1].y, vl[r*4+1].z, vl[r*4+1].w};
                float c2[4] = {vl[r*4+2].x, vl[r*4+2].y, vl[r*4+2].z, vl[r*4+2].w};
                float c3[4] = {vl[r*4+3].x, vl[r*4+3].y, vl[r*4+3].z, vl[r*4+3].w};
                #pragma unroll
                for (int p = 0; p < 4; ++p) {
                    float f0 = gval[r] ? c0[p] : 0.f;
                    float f1 = gval[r] ? c1[p] : 0.f;
                    float f2 = gval[r] ? c2[p] : 0.f;
                    float f3 = gval[r] ? c3[p] : 0.f;
                    __hip_bfloat162 u01 = __float22bfloat162_rn(make_float2(f0, f1));
                    __hip_bfloat162 u23 = __float22bfloat162_rn(make_float2(f2, f3));
                    uint2 wv;
                    wv.x = *reinterpret_cast<unsigned*>(&u01);
                    wv.y = *reinterpret_cast<unsigned*>(&u23);
                    *reinterpret_cast<uint2*>(&Bb[nxt][lbase[r] + p * 8]) = wv;
                }
            }
        }
        __syncthreads();
    }

    // ---- store: oc = m*32 + (reg&3) + 8*(reg>>2) + 4*h ; px = j*32+ln ----
    #pragma unroll
    for (int m = 0; m < 2; ++m) {
        #pragma unroll
        for (int j = 0; j < 4; ++j) {
            if (j == 3 && ln >= 16) continue;   // px >= 112
            float* ob = out + ((size_t)(b * OCn + m * 32 + 4 * h)) * NPIX
                            + (y0 + w) * WW + j * 32 + ln;
            #pragma unroll
            for (int reg = 0; reg < 16; ++reg) {
                int row = (reg & 3) + 8 * (reg >> 2);
                ob[(size_t)row * NPIX] = acc[m][j][reg];
            }
        }
    }
}

// ---------------- fallback (round-5 structure, no ws) ----------------
#define ICP 24
#define WSTRIDE 152
__global__ __launch_bounds__(256, 2)
void adaconv_fallback(const float* __restrict__ x,
                      const float* __restrict__ kb,
                      const float* __restrict__ km,
                      const int* __restrict__ label,
                      const int* __restrict__ epoch,
                      float* __restrict__ out)
{
    __shared__ unsigned short Xs[18][34][ICP];
    __shared__ unsigned short Ws[64][WSTRIDE];

    const int tid = threadIdx.x;
    const int b   = blockIdx.y;
    const int bx  = blockIdx.x & 3;
    const int byy = blockIdx.x >> 2;
    const int x0 = bx * 32, y0 = byy * 16;

    int d = (epoch[0] >= FUSE_EPOCH) ? 0 : label[b];
    d &= 3;

    const int w    = tid >> 6;
    const int lane = tid & 63;
    const int ln   = lane & 31;
    const int h    = lane >> 5;

    f32x16 acc[2][4];
    #pragma unroll
    for (int m = 0; m < 2; ++m)
        #pragma unroll
        for (int j = 0; j < 4; ++j)
            #pragma unroll
            for (int k = 0; k < 16; ++k) acc[m][j][k] = 0.f;

    const float* xb = x + (size_t)b * ICn * HH * WW;

    for (int ck = 0; ck < 4; ++ck) {
        const int icb = ck * 16;
        __syncthreads();
        for (int idx = tid; idx < 18 * 34 * 16; idx += 256) {
            int ic  = idx / 612;
            int rem = idx - ic * 612;
            int r   = rem / 34;
            int c   = rem - r * 34;
            int gy = y0 - 1 + r, gx = x0 - 1 + c;
            float v = 0.f;
            if ((unsigned)gy < HH && (unsigned)gx < WW)
                v = xb[(size_t)(icb + ic) * (HH * WW) + gy * WW + gx];
            Xs[r][c][ic] = f2bf(v);
        }
        for (int i = tid; i < 9216; i += 256) {
            int ic_ = i & 15;
            int tt  = (i >> 4) % 9;
            int oc  = i / 144;
            int ic  = icb + ic_;
            Ws[oc][tt * 16 + ic_] = f2bf(kb[(oc * ICn + ic) * 9 + tt] * km[(d * ICn + ic) * 9 + tt]);
        }
        __syncthreads();
        #pragma unroll
        for (int kh = 0; kh < 3; ++kh)
            #pragma unroll
            for (int kw = 0; kw < 3; ++kw) {
                const int t = kh * 3 + kw;
                short8 a0 = *reinterpret_cast<const short8*>(&Ws[ln][t * 16 + h * 8]);
                short8 a1 = *reinterpret_cast<const short8*>(&Ws[32 + ln][t * 16 + h * 8]);
                #pragma unroll
                for (int rj = 0; rj < 4; ++rj) {
                    short8 bb2 = *reinterpret_cast<const short8*>(&Xs[4 * w + rj + kh][ln + kw][h * 8]);
                    acc[0][rj] = __builtin_amdgcn_mfma_f32_32x32x16_bf16(a0, bb2, acc[0][rj], 0, 0, 0);
                    acc[1][rj] = __builtin_amdgcn_mfma_f32_32x32x16_bf16(a1, bb2, acc[1][rj], 0, 0, 0);
                }
            }
    }

    const int xg = x0 + ln;
    if (xg < WW) {
        #pragma unroll
        for (int m = 0; m < 2; ++m)
            #pragma unroll
            for (int rj = 0; rj < 4; ++rj) {
                const int yg = y0 + 4 * w + rj;
                #pragma unroll
                for (int reg = 0; reg < 16; ++reg) {
                    const int row = (reg & 3) + 8 * (reg >> 2) + 4 * h;
                    out[(((size_t)b * OCn + m * 32 + row) * HH + yg) * WW + xg] = acc[m][rj][reg];
                }
            }
    }
}

extern "C" void kernel_launch(void* const* d_in, const int* in_sizes, int n_in,
                              void* d_out, int out_size, void* d_ws, size_t ws_size,
                              hipStream_t stream) {
    const float* x  = (const float*)d_in[0];
    const float* kb = (const float*)d_in[1];
    const float* km = (const float*)d_in[2];
    const int*   lb = (const int*)d_in[3];
    const int*   ep = (const int*)d_in[4];
    float* out = (float*)d_out;

    if (ws_size >= WF_BYTES) {
        unsigned short* wf2 = (unsigned short*)d_ws;
        fuse_w_kernel<<<576, 256, 0, stream>>>(kb, km, wf2);
        adaconv_fused<<<1792, 256, 0, stream>>>(x, wf2, lb, ep, out);
    } else {
        adaconv_fallback<<<dim3(28, 64), 256, 0, stream>>>(x, kb, km, lb, ep, out);
    }
}

// Round 27
// 116.721 us; speedup vs baseline: 1.0960x; 1.0960x over previous
//
#include <hip/hip_runtime.h>
#include <hip/hip_bf16.h>

// AdaConv2d: per-sample conv, kernel = base * mask[label[b]] (oc-indep mask).
// B=64, IC=OC=64, H=W=112, 3x3, pad 1. fp32 in/out.
//
// Round 26: FINAL = exact revert to round 24 (best measured: 117.5us).
// R25's A-from-global regressed (-10us: per-tap VMEM loads on the MFMA
// critical path, latency not hidden at 2 blocks/CU). R24 = fused direct-x
// implicit GEMM (1 main kernel + tiny weight-fuse prepass): per-ck double-
// buffered LDS for B (fp32 loads + cvt + ds_write) and A (global_load_lds),
// T1 XCD-bijective block swizzle (FETCH 161->105MB), T5 setprio, 2x4 32x32
// MFMA acc/wave. Journey: 924us fp32 VALU -> 418 LDS-MFMA -> 233 ws-Xt ->
// 174 tuned -> 119.4 fused -> 117.5 (+T1).

#define HH 112
#define WW 112
#define ICn 64
#define OCn 64
#define FUSE_EPOCH 9
#define NPIX (HH * WW)

typedef __attribute__((ext_vector_type(8)))  short  short8;
typedef __attribute__((ext_vector_type(8)))  unsigned short bf8;
typedef __attribute__((ext_vector_type(16))) float  f32x16;
typedef unsigned int u32;

#define WF_BYTES ((size_t)4 * 64 * 576 * 2)

static __device__ __forceinline__ unsigned short f2bf(float v) {
    __hip_bfloat16 hb = __float2bfloat16(v);
    return *reinterpret_cast<unsigned short*>(&hb);
}

static __device__ __forceinline__ void gload16(const unsigned short* g, unsigned short* l) {
    __builtin_amdgcn_global_load_lds(
        (const __attribute__((address_space(1))) u32*)g,
        (__attribute__((address_space(3))) u32*)l, 16, 0, 0);
}

// -------- fused weights: wf2[d][ck][t][h][oc][8e], ic = ck*16+h*8+e --------
__global__ __launch_bounds__(256)
void fuse_w_kernel(const float* __restrict__ kb, const float* __restrict__ km,
                   unsigned short* __restrict__ wf2)
{
    int idx = blockIdx.x * 256 + threadIdx.x;
    if (idx >= 4 * 4 * 9 * 2 * 64 * 8) return;
    int e  = idx & 7;
    int oc = (idx >> 3) & 63;
    int h  = (idx >> 9) & 1;
    int r  = idx >> 10;          // t + 9*(ck + 4*d)
    int t  = r % 9; r /= 9;
    int ck = r & 3;
    int d  = r >> 2;
    int ic = ck * 16 + h * 8 + e;
    wf2[idx] = f2bf(kb[(oc * ICn + ic) * 9 + t] * km[(d * ICn + ic) * 9 + t]);
}

// ------------------- fused main: direct-x implicit GEMM -------------------
__global__ __launch_bounds__(256, 2)
void adaconv_fused(const float* __restrict__ x,
                   const unsigned short* __restrict__ wf2,
                   const int* __restrict__ label,
                   const int* __restrict__ epoch,
                   float* __restrict__ out)
{
    // B: [6 rows][2 hh][114 px][8 ic] bf16 = 21888 B per buffer
    // A: [9 t][2 hh][64 oc][8 e]      bf16 = 18432 B per buffer
    __shared__ unsigned short Bb[2][10944];
    __shared__ unsigned short Ab[2][9216];

    const int tid  = threadIdx.x;
    // T1: XCD-bijective swizzle. 1792 blocks = 8 XCD x 224; XCD owns 8 samples.
    const int lid  = blockIdx.x;
    const int wgid = (lid & 7) * 224 + (lid >> 3);
    const int b    = wgid / 28;
    const int y0   = (wgid % 28) * 4;
    const int w    = tid >> 6;           // wave 0..3 = out-row y0+w
    const int lane = tid & 63;
    const int ln   = lane & 31;
    const int h    = lane >> 5;          // K-half

    int d = (epoch[0] >= FUSE_EPOCH) ? 0 : label[b];
    d &= 3;
    const unsigned short* wfd = wf2 + (size_t)d * 36864;

    // ---- per-thread B-staging descriptors (672 items, 3 rounds) ----
    // item c = (((lr*2+hh)*2 + icq)*28 + seg): 4 ics x 4 px at (row lr, hh)
    const float* ga[12];
    int  lbase[3];
    bool wact[3], gval[3];
    #pragma unroll
    for (int r = 0; r < 3; ++r) {
        int c = r * 256 + tid;
        bool a = (c < 672);
        int cc = a ? c : 671;
        int seg = cc % 28;
        int q   = cc / 28;
        int icq = q & 1;
        int rh  = q >> 1;              // lr*2+hh
        int lr  = rh >> 1;
        int hh  = rh & 1;
        int gy  = y0 - 1 + lr;
        bool v  = ((unsigned)gy < 112u);
        wact[r] = a;
        gval[r] = v;
        lbase[r] = (rh * 114 + 4 * seg + 1) * 8 + icq * 4;
        int icl = hh * 8 + icq * 4;    // ic within 16-chunk
        #pragma unroll
        for (int i = 0; i < 4; ++i)
            ga[r * 4 + i] = x + ((size_t)(b * 64 + icl + i) * 112 + (v ? gy : 0)) * 112 + 4 * seg;
    }

    auto issueA = [&](int buf, int ck1) {
        #pragma unroll
        for (int r = 0; r < 5; ++r) {
            int c = r * 256 + tid;
            if (c < 1152)
                gload16(wfd + ck1 * 9216 + (size_t)c * 8, &Ab[buf][(r * 256 + w * 64) * 8]);
        }
    };

    f32x16 acc[2][4];
    #pragma unroll
    for (int m = 0; m < 2; ++m)
        #pragma unroll
        for (int j = 0; j < 4; ++j)
            #pragma unroll
            for (int k = 0; k < 16; ++k) acc[m][j][k] = 0.f;

    const int bb = (w * 228 + h * 114 + ln) * 8;   // + (kh*228+kw+j*32)*8
    const int ab = h * 512 + ln * 8;               // + m*256 + t*1024

    // ---- prologue: zero edge px {0,113} in both buffers; stage ck=0 ----
    if (tid < 48) {
        int bz = tid / 24, z = tid % 24;
        int rh = z >> 1, px = (z & 1) ? 113 : 0;
        bf8 zz = bf8{0,0,0,0,0,0,0,0};
        *reinterpret_cast<bf8*>(&Bb[bz][(rh * 114 + px) * 8]) = zz;
    }
    {
        float4 vl[12];
        #pragma unroll
        for (int r = 0; r < 3; ++r)
            if (wact[r])
                #pragma unroll
                for (int i = 0; i < 4; ++i)
                    vl[r * 4 + i] = *reinterpret_cast<const float4*>(ga[r * 4 + i]);
        issueA(0, 0);
        // convert + write B(0)
        #pragma unroll
        for (int r = 0; r < 3; ++r) {
            if (!wact[r]) continue;
            float c0[4] = {vl[r*4+0].x, vl[r*4+0].y, vl[r*4+0].z, vl[r*4+0].w};
            float c1[4] = {vl[r*4+1].x, vl[r*4+1].y, vl[r*4+1].z, vl[r*4+1].w};
            float c2[4] = {vl[r*4+2].x, vl[r*4+2].y, vl[r*4+2].z, vl[r*4+2].w};
            float c3[4] = {vl[r*4+3].x, vl[r*4+3].y, vl[r*4+3].z, vl[r*4+3].w};
            #pragma unroll
            for (int p = 0; p < 4; ++p) {
                float f0 = gval[r] ? c0[p] : 0.f;
                float f1 = gval[r] ? c1[p] : 0.f;
                float f2 = gval[r] ? c2[p] : 0.f;
                float f3 = gval[r] ? c3[p] : 0.f;
                __hip_bfloat162 u01 = __float22bfloat162_rn(make_float2(f0, f1));
                __hip_bfloat162 u23 = __float22bfloat162_rn(make_float2(f2, f3));
                uint2 wv;
                wv.x = *reinterpret_cast<unsigned*>(&u01);
                wv.y = *reinterpret_cast<unsigned*>(&u23);
                *reinterpret_cast<uint2*>(&Bb[0][lbase[r] + p * 8]) = wv;
            }
        }
        __syncthreads();
    }

    // ---- main loop: issue(nxt) -> compute(cur) -> cvt+write(nxt) -> barrier
    #pragma unroll
    for (int ck = 0; ck < 4; ++ck) {
        const int cur = ck & 1, nxt = cur ^ 1;
        float4 vl[12];
        if (ck < 3) {
            #pragma unroll
            for (int r = 0; r < 3; ++r)
                if (wact[r])
                    #pragma unroll
                    for (int i = 0; i < 4; ++i)
                        vl[r * 4 + i] = *reinterpret_cast<const float4*>(
                            ga[r * 4 + i] + (size_t)(ck + 1) * 200704);
            issueA(nxt, ck + 1);
            __builtin_amdgcn_sched_barrier(0);   // keep issues above compute
        }

        const unsigned short* Bc = Bb[cur];
        const unsigned short* Ac = Ab[cur];
        __builtin_amdgcn_s_setprio(1);           // T5: favor MFMA-issuing wave
        #pragma unroll
        for (int kh = 0; kh < 3; ++kh) {
            #pragma unroll
            for (int kw = 0; kw < 3; ++kw) {
                const int t = kh * 3 + kw;
                short8 a0 = *reinterpret_cast<const short8*>(&Ac[ab + t * 1024]);
                short8 a1 = *reinterpret_cast<const short8*>(&Ac[ab + 256 + t * 1024]);
                #pragma unroll
                for (int j = 0; j < 4; ++j) {
                    short8 bj = *reinterpret_cast<const short8*>(
                        &Bc[bb + (kh * 228 + kw + j * 32) * 8]);
                    acc[0][j] = __builtin_amdgcn_mfma_f32_32x32x16_bf16(a0, bj, acc[0][j], 0, 0, 0);
                    acc[1][j] = __builtin_amdgcn_mfma_f32_32x32x16_bf16(a1, bj, acc[1][j], 0, 0, 0);
                }
            }
        }
        __builtin_amdgcn_s_setprio(0);

        if (ck < 3) {
            #pragma unroll
            for (int r = 0; r < 3; ++r) {
                if (!wact[r]) continue;
                float c0[4] = {vl[r*4+0].x, vl[r*4+0].y, vl[r*4+0].z, vl[r*4+0].w};
                float c1[4] = {vl[r*4+1].x, vl[r*4+1].y, vl[r*4+1].z, vl[r*4+1].w};
                float c2[4] = {vl[r*4+2].x, vl[r*4+2].y, vl[r*4+2].z, vl[r*4+2].w};
                float c3[4] = {vl[r*4+3].x, vl[r*4+3].y, vl[r*4+3].z, vl[r*4+3].w};
                #pragma unroll
                for (int p = 0; p < 4; ++p) {
                    float f0 = gval[r] ? c0[p] : 0.f;
                    float f1 = gval[r] ? c1[p] : 0.f;
                    float f2 = gval[r] ? c2[p] : 0.f;
                    float f3 = gval[r] ? c3[p] : 0.f;
                    __hip_bfloat162 u01 = __float22bfloat162_rn(make_float2(f0, f1));
                    __hip_bfloat162 u23 = __float22bfloat162_rn(make_float2(f2, f3));
                    uint2 wv;
                    wv.x = *reinterpret_cast<unsigned*>(&u01);
                    wv.y = *reinterpret_cast<unsigned*>(&u23);
                    *reinterpret_cast<uint2*>(&Bb[nxt][lbase[r] + p * 8]) = wv;
                }
            }
        }
        __syncthreads();
    }

    // ---- store: oc = m*32 + (reg&3) + 8*(reg>>2) + 4*h ; px = j*32+ln ----
    #pragma unroll
    for (int m = 0; m < 2; ++m) {
        #pragma unroll
        for (int j = 0; j < 4; ++j) {
            if (j == 3 && ln >= 16) continue;   // px >= 112
            float* ob = out + ((size_t)(b * OCn + m * 32 + 4 * h)) * NPIX
                            + (y0 + w) * WW + j * 32 + ln;
            #pragma unroll
            for (int reg = 0; reg < 16; ++reg) {
                int row = (reg & 3) + 8 * (reg >> 2);
                ob[(size_t)row * NPIX] = acc[m][j][reg];
            }
        }
    }
}

// ---------------- fallback (round-5 structure, no ws) ----------------
#define ICP 24
#define WSTRIDE 152
__global__ __launch_bounds__(256, 2)
void adaconv_fallback(const float* __restrict__ x,
                      const float* __restrict__ kb,
                      const float* __restrict__ km,
                      const int* __restrict__ label,
                      const int* __restrict__ epoch,
                      float* __restrict__ out)
{
    __shared__ unsigned short Xs[18][34][ICP];
    __shared__ unsigned short Ws[64][WSTRIDE];

    const int tid = threadIdx.x;
    const int b   = blockIdx.y;
    const int bx  = blockIdx.x & 3;
    const int byy = blockIdx.x >> 2;
    const int x0 = bx * 32, y0 = byy * 16;

    int d = (epoch[0] >= FUSE_EPOCH) ? 0 : label[b];
    d &= 3;

    const int w    = tid >> 6;
    const int lane = tid & 63;
    const int ln   = lane & 31;
    const int h    = lane >> 5;

    f32x16 acc[2][4];
    #pragma unroll
    for (int m = 0; m < 2; ++m)
        #pragma unroll
        for (int j = 0; j < 4; ++j)
            #pragma unroll
            for (int k = 0; k < 16; ++k) acc[m][j][k] = 0.f;

    const float* xb = x + (size_t)b * ICn * HH * WW;

    for (int ck = 0; ck < 4; ++ck) {
        const int icb = ck * 16;
        __syncthreads();
        for (int idx = tid; idx < 18 * 34 * 16; idx += 256) {
            int ic  = idx / 612;
            int rem = idx - ic * 612;
            int r   = rem / 34;
            int c   = rem - r * 34;
            int gy = y0 - 1 + r, gx = x0 - 1 + c;
            float v = 0.f;
            if ((unsigned)gy < HH && (unsigned)gx < WW)
                v = xb[(size_t)(icb + ic) * (HH * WW) + gy * WW + gx];
            Xs[r][c][ic] = f2bf(v);
        }
        for (int i = tid; i < 9216; i += 256) {
            int ic_ = i & 15;
            int tt  = (i >> 4) % 9;
            int oc  = i / 144;
            int ic  = icb + ic_;
            Ws[oc][tt * 16 + ic_] = f2bf(kb[(oc * ICn + ic) * 9 + tt] * km[(d * ICn + ic) * 9 + tt]);
        }
        __syncthreads();
        #pragma unroll
        for (int kh = 0; kh < 3; ++kh)
            #pragma unroll
            for (int kw = 0; kw < 3; ++kw) {
                const int t = kh * 3 + kw;
                short8 a0 = *reinterpret_cast<const short8*>(&Ws[ln][t * 16 + h * 8]);
                short8 a1 = *reinterpret_cast<const short8*>(&Ws[32 + ln][t * 16 + h * 8]);
                #pragma unroll
                for (int rj = 0; rj < 4; ++rj) {
                    short8 bb2 = *reinterpret_cast<const short8*>(&Xs[4 * w + rj + kh][ln + kw][h * 8]);
                    acc[0][rj] = __builtin_amdgcn_mfma_f32_32x32x16_bf16(a0, bb2, acc[0][rj], 0, 0, 0);
                    acc[1][rj] = __builtin_amdgcn_mfma_f32_32x32x16_bf16(a1, bb2, acc[1][rj], 0, 0, 0);
                }
            }
    }

    const int xg = x0 + ln;
    if (xg < WW) {
        #pragma unroll
        for (int m = 0; m < 2; ++m)
            #pragma unroll
            for (int rj = 0; rj < 4; ++rj) {
                const int yg = y0 + 4 * w + rj;
                #pragma unroll
                for (int reg = 0; reg < 16; ++reg) {
                    const int row = (reg & 3) + 8 * (reg >> 2) + 4 * h;
                    out[(((size_t)b * OCn + m * 32 + row) * HH + yg) * WW + xg] = acc[m][rj][reg];
                }
            }
    }
}

extern "C" void kernel_launch(void* const* d_in, const int* in_sizes, int n_in,
                              void* d_out, int out_size, void* d_ws, size_t ws_size,
                              hipStream_t stream) {
    const float* x  = (const float*)d_in[0];
    const float* kb = (const float*)d_in[1];
    const float* km = (const float*)d_in[2];
    const int*   lb = (const int*)d_in[3];
    const int*   ep = (const int*)d_in[4];
    float* out = (float*)d_out;

    if (ws_size >= WF_BYTES) {
        unsigned short* wf2 = (unsigned short*)d_ws;
        fuse_w_kernel<<<576, 256, 0, stream>>>(kb, km, wf2);
        adaconv_fused<<<1792, 256, 0, stream>>>(x, wf2, lb, ep, out);
    } else {
        adaconv_fallback<<<dim3(28, 64), 256, 0, stream>>>(x, kb, km, lb, ep, out);
    }
}